// Round 10
// baseline (105.800 us; speedup 1.0000x reference)
//
#include <hip/hip_runtime.h>
#include <hip/hip_bf16.h>

// TripletLoss, N=8192, D=256 fp32, targets in [0,128).
// out[0] = mean(relu(dist_ap - dist_an + 0.3)), out[1] = mean(dist_an > dist_ap)
// dist = sqrt(clip(sq_i + sq_j - 2 dot, 1e-12)); sqrt deferred (monotone);
// clipped d2 >= 0 so uint-bit order == float order -> atomicMax/Min unsigned.
//
// R15: 3 BLOCKS/CU. Cross-round calibration (R7/R10/R13/R14): T_block is
// PHASE-COUNT-bound (~1.5us/phase vs ~0.3us of work) regardless of tile
// width -> the per-phase latency stall only hides under independent
// phase-shifted blocks. R14's 256x128 shape caps at 2 blocks/CU; the 128x128
// shape + R14's LDS diet = 50.5KB -> 3 blocks/CU (151.5KB < 160KiB), 12
// waves/CU in 3 independent streams. 2080 blocks / 768 slots = 2.7 rounds.
//  - Body: R7 geometry (4 DMA loads/thread/phase, vmcnt(4) ladder) + R8
//    single-barrier ledger + R14 direct-RMW epilogue (no LDS reduction
//    arrays) + fused finish via arrival counter. All proven, absmax 0.
//  - __launch_bounds__(256,3): 3 waves/EU floor so regalloc fits 3 blocks.
//  - SQ_LDS_BANK_CONFLICT ~2.16M = global_load_lds DMA-write artifact.
//  - Score model: ~45us poison fill (uncontrollable) + prep + gaps + tile.

#define N 8192
#define D 256
#define MARGIN 0.3f
#define NBLK 2080  // 64*65/2 lower-triangle 128x128 tiles

typedef __bf16  bf16x8  __attribute__((ext_vector_type(8)));
typedef float   floatx4 __attribute__((ext_vector_type(4)));

__device__ __forceinline__ void load_lds16(const void* g, void* s) {
  __builtin_amdgcn_global_load_lds(
      (const __attribute__((address_space(1))) void*)g,
      (__attribute__((address_space(3))) void*)s, 16, 0, 0);
}

// ---------------- Kernel A: bf16 cast + row sq-norms + init ------------------
__global__ __launch_bounds__(256) void prep_kernel(
    const float* __restrict__ X, unsigned short* __restrict__ Xb,
    float* __restrict__ sq, unsigned* __restrict__ pmax, unsigned* __restrict__ nmin,
    unsigned* __restrict__ cnt) {
  const int t = threadIdx.x;
  if (blockIdx.x == 0 && t == 0) *cnt = 0u;  // re-poison arrival counter
  const int lane = t & 63, wave = t >> 6;
  const int row0 = blockIdx.x * 8 + wave * 2;
#pragma unroll
  for (int r = 0; r < 2; ++r) {
    const int row = row0 + r;
    float4 v = *reinterpret_cast<const float4*>(X + (size_t)row * D + lane * 4);
    ushort4 h;
    {
      __hip_bfloat16 b0 = __float2bfloat16(v.x), b1 = __float2bfloat16(v.y);
      __hip_bfloat16 b2 = __float2bfloat16(v.z), b3 = __float2bfloat16(v.w);
      h.x = *reinterpret_cast<unsigned short*>(&b0);
      h.y = *reinterpret_cast<unsigned short*>(&b1);
      h.z = *reinterpret_cast<unsigned short*>(&b2);
      h.w = *reinterpret_cast<unsigned short*>(&b3);
    }
    *reinterpret_cast<ushort4*>(Xb + (size_t)row * D + lane * 4) = h;
    float s = v.x * v.x + v.y * v.y + v.z * v.z + v.w * v.w;
#pragma unroll
    for (int o = 32; o > 0; o >>= 1) s += __shfl_down(s, o);
    if (lane == 0) {
      sq[row] = s;
      pmax[row] = 0u;
      nmin[row] = 0x7F800000u;  // +inf
    }
  }
}

// ---------------- Kernel B: 128x128 tiles, 4 waves, 3 blocks/CU --------------
__global__ __launch_bounds__(256, 3) void tile_kernel(
    const unsigned short* __restrict__ Xb, const float* __restrict__ sq,
    const int* __restrict__ tgt, unsigned* __restrict__ pmax,
    unsigned* __restrict__ nmin, unsigned* __restrict__ cnt,
    float* __restrict__ out) {
  // T1: XCD-aware swizzle; NBLK % 8 == 0 (2080 = 8*260), bijective.
  const int hw = blockIdx.x;
  const int bi = (hw & 7) * (NBLK / 8) + (hw >> 3);

  // lower-triangle decode: bi -> (by >= bx)
  int by = (int)((sqrtf(8.0f * (float)bi + 1.0f) - 1.0f) * 0.5f);
  while ((by + 1) * (by + 2) / 2 <= bi) ++by;
  while (by * (by + 1) / 2 > bi) --by;
  const int bx = bi - by * (by + 1) / 2;
  const int rowBase = by * 128, colBase = bx * 128;

  const int t = threadIdx.x;
  const int lane = t & 63, wave = t >> 6;
  const int wy = wave >> 1, wx = wave & 1;   // wave-tile 64x64
  const int quad = lane >> 4, l15 = lane & 15;

  // 3-deep rotating buffers: A 128x32 (8KB) x3, B 128x32 (8KB) x3 = 48 KB
  __shared__ __align__(16) unsigned short As[3][128 * 32];
  __shared__ __align__(16) unsigned short Bs[3][128 * 32];
  __shared__ float sqr[128], sqc[128];
  __shared__ unsigned char tr8[128], tc8[128];   // targets in [0,128) fit u8
  __shared__ unsigned lastFlag;
  __shared__ float fls[4], fps[4];
  // NO LDS reduction arrays (R14): butterfly results -> direct global RMWs.

  if (t < 128) {
    sqr[t] = sq[rowBase + t]; tr8[t] = (unsigned char)tgt[rowBase + t];
  } else {
    int u = t - 128;
    sqc[u] = sq[colBase + u]; tc8[u] = (unsigned char)tgt[colBase + u];
  }

  const unsigned short* Ag = Xb + (size_t)rowBase * D;
  const unsigned short* Bg = Xb + (size_t)colBase * D;

  // DMA source pre-swizzle (both sides or neither): LDS slot s of row holds
  // global chunk s ^ f(row), f(x) = (x + (x>>2)) & 3; f invariant under
  // +16/+64 multiples -> one base + immediates everywhere.
  // 256 threads cover the 512 16B-slots of a tile in 2 iterations.
  const int r0 = t >> 2;                              // 0..63
  const int cA = (t & 3) ^ ((r0 + (r0 >> 2)) & 3);
  const int g0 = r0 * D + cA * 8;                     // elements; it=1: +64*D
  const int lb0 = wave * 1024;                        // slots [wave*64, +64)
  const int lb1 = 4096 + wave * 1024;                 // slots [256+wave*64, +64)

  const int fq  = (l15 + (l15 >> 2)) & 3;
  const int aA0 = ((wy * 64 + l15) * 4 + (quad ^ fq)) * 16;  // +mi*1024 +buf*8192
  const int bA0 = ((wx * 64 + l15) * 4 + (quad ^ fq)) * 16;  // +nj*1024 +buf*8192
  const char* AsB = (const char*)As;
  const char* BsB = (const char*)Bs;

  floatx4 acc[4][4];
#pragma unroll
  for (int mi = 0; mi < 4; ++mi)
#pragma unroll
    for (int nj = 0; nj < 4; ++nj)
      acc[mi][nj] = (floatx4){0.f, 0.f, 0.f, 0.f};

  // 4 DMA loads/thread/phase: A rows r0, r0+64; B rows r0, r0+64.
#define ISSUE_DMA(ph) do {                                                   \
    const int ko_ = (ph) * 32;                                               \
    char* an_ = (char*)As[(ph) % 3];                                         \
    char* bn_ = (char*)Bs[(ph) % 3];                                         \
    load_lds16(Ag + g0 + ko_,          an_ + lb0);                           \
    load_lds16(Ag + g0 + 64 * D + ko_, an_ + lb1);                           \
    load_lds16(Bg + g0 + ko_,          bn_ + lb0);                           \
    load_lds16(Bg + g0 + 64 * D + ko_, bn_ + lb1);                           \
  } while (0)

  // Single barrier per phase (R8 ledger): vmcnt(own group of 4; group k+1
  // outstanding -> VM=4; tail 0) BEFORE the barrier -> tile k%3 valid
  // cross-wave at exit; ISSUE k+2 after the barrier overwrites buf (k-1)%3
  // whose reads every wave secured via lgkmcnt(0) before arriving.
#define PHASE(kk, VM) do {                                                   \
    asm volatile("s_waitcnt vmcnt(" #VM ")" ::: "memory");                   \
    __builtin_amdgcn_s_barrier();                                            \
    __builtin_amdgcn_sched_barrier(0);                                       \
    const char* ab_ = AsB + ((kk) % 3) * 8192;                               \
    const char* bb_ = BsB + ((kk) % 3) * 8192;                               \
    bf16x8 a_[4], b_[4];                                                     \
    _Pragma("unroll")                                                        \
    for (int mi = 0; mi < 4; ++mi)                                           \
      a_[mi] = *reinterpret_cast<const bf16x8*>(ab_ + aA0 + mi * 1024);      \
    _Pragma("unroll")                                                        \
    for (int nj = 0; nj < 4; ++nj)                                           \
      b_[nj] = *reinterpret_cast<const bf16x8*>(bb_ + bA0 + nj * 1024);      \
    if ((kk) < 6) ISSUE_DMA((kk) + 2);                                       \
    asm volatile("s_waitcnt lgkmcnt(0)" ::: "memory");                       \
    __builtin_amdgcn_sched_barrier(0);                                       \
    __builtin_amdgcn_s_setprio(1);                                           \
    _Pragma("unroll")                                                        \
    for (int mi = 0; mi < 4; ++mi)                                           \
      _Pragma("unroll")                                                      \
      for (int nj = 0; nj < 4; ++nj)                                         \
        acc[mi][nj] = __builtin_amdgcn_mfma_f32_16x16x32_bf16(               \
            a_[mi], b_[nj], acc[mi][nj], 0, 0, 0);                           \
    __builtin_amdgcn_s_setprio(0);                                           \
    __builtin_amdgcn_sched_barrier(0);                                       \
  } while (0)

  // prologue: phases 0 and 1 in flight (8 loads/thread outstanding)
  ISSUE_DMA(0);
  ISSUE_DMA(1);

  PHASE(0, 4);
  PHASE(1, 4);
  PHASE(2, 4);
  PHASE(3, 4);
  PHASE(4, 4);
  PHASE(5, 4);
  PHASE(6, 4);
  PHASE(7, 0);

#undef PHASE
#undef ISSUE_DMA

  // ---- two-sided epilogue on UNclipped d2 (clip re-applied at pushes) ----
  float sqc_l[4]; int tc_l[4];
#pragma unroll
  for (int nj = 0; nj < 4; ++nj) {
    int jl = wx * 64 + nj * 16 + l15;
    sqc_l[nj] = sqc[jl];
    tc_l[nj]  = tc8[jl];
  }

  float pm[16], nm[16], cmP[4], cmN[4];
#pragma unroll
  for (int s = 0; s < 16; ++s) { pm[s] = 0.f; nm[s] = __builtin_huge_valf(); }
#pragma unroll
  for (int nj = 0; nj < 4; ++nj) { cmP[nj] = 0.f; cmN[nj] = __builtin_huge_valf(); }

#pragma unroll
  for (int mi = 0; mi < 4; ++mi) {
#pragma unroll
    for (int r = 0; r < 4; ++r) {
      int il = wy * 64 + mi * 16 + quad * 4 + r;
      float si = sqr[il];
      int   ti = tr8[il];
      int   s  = mi * 4 + r;
#pragma unroll
      for (int nj = 0; nj < 4; ++nj) {
        float d2 = fmaf(-2.f, acc[mi][nj][r], si + sqc_l[nj]);  // unclipped
        bool same = (ti == tc_l[nj]);
        // 0-identity pre-clip safe for max: diagonal guarantees true
        // pmax >= 1e-12; clip re-applied before the ordered atomics.
        float selP = same ? d2 : 0.f;
        float selN = same ? __builtin_huge_valf() : d2;
        pm[s]   = fmaxf(pm[s], selP);
        nm[s]   = fminf(nm[s], selN);
        cmP[nj] = fmaxf(cmP[nj], selP);
        cmN[nj] = fminf(cmN[nj], selN);
      }
    }
  }

  // row-side halving butterfly across 16 lanes of each quad group
#pragma unroll
  for (int m = 8; m >= 1; m >>= 1) {
#pragma unroll
    for (int j = 0; j < m; ++j) {
      bool up = (l15 & m) != 0;
      float sp = up ? pm[j] : pm[j + m];
      float sn = up ? nm[j] : nm[j + m];
      float rp = __shfl_xor(sp, m);
      float rn = __shfl_xor(sn, m);
      float kp = up ? pm[j + m] : pm[j];
      float kn = up ? nm[j + m] : nm[j];
      pm[j] = fmaxf(kp, rp);
      nm[j] = fminf(kn, rn);
    }
  }

  // DIRECT global RMWs (clip first: sign trick needs >= 0). Returns captured
  // (sc0) so vmcnt(0) below proves commit at the device-coherent point.
  // wx=0/1 waves push the same row addresses (idempotent max/min) - correct.
  unsigned keep;
  {
    int rowIdx = wy * 64 + ((l15 >> 2) << 4) + (quad << 2) + (l15 & 3);
    unsigned o1 = atomicMax(&pmax[rowBase + rowIdx], __float_as_uint(fmaxf(pm[0], 1e-12f)));
    unsigned o2 = atomicMin(&nmin[rowBase + rowIdx], __float_as_uint(fmaxf(nm[0], 1e-12f)));
    keep = o1 ^ o2;
  }

  // col-side: reduce across quads, then direct global RMW
#pragma unroll
  for (int nj = 0; nj < 4; ++nj) {
    cmP[nj] = fmaxf(cmP[nj], __shfl_xor(cmP[nj], 16));
    cmP[nj] = fmaxf(cmP[nj], __shfl_xor(cmP[nj], 32));
    cmN[nj] = fminf(cmN[nj], __shfl_xor(cmN[nj], 16));
    cmN[nj] = fminf(cmN[nj], __shfl_xor(cmN[nj], 32));
  }
  {
    float vP = (quad == 0) ? cmP[0] : (quad == 1) ? cmP[1] : (quad == 2) ? cmP[2] : cmP[3];
    float vN = (quad == 0) ? cmN[0] : (quad == 1) ? cmN[1] : (quad == 2) ? cmN[2] : cmN[3];
    int colIdx = wx * 64 + quad * 16 + l15;
    unsigned o3 = atomicMax(&pmax[colBase + colIdx], __float_as_uint(fmaxf(vP, 1e-12f)));
    unsigned o4 = atomicMin(&nmin[colBase + colIdx], __float_as_uint(fmaxf(vN, 1e-12f)));
    keep ^= o3 ^ o4;
  }
  asm volatile("" :: "v"(keep));  // keep returns live (no DCE of sc0)
  asm volatile("s_waitcnt vmcnt(0)" ::: "memory");
  __syncthreads();

  // arrival counter: all RMWs committed at the coherent point; no dirty
  // plain stores exist -> no wbl2 fence needed (the R3/R4 trap).
  if (t == 0) lastFlag = (atomicAdd(cnt, 1u) == NBLK - 1u) ? 1u : 0u;
  __syncthreads();

  if (lastFlag) {
    // ---- fused finish: agent-scope coherent loads, fully pipelined ----
    float lsum = 0.f, psum = 0.f;
#pragma unroll 4
    for (int i = t; i < N; i += 256) {
      unsigned pu = __hip_atomic_load(&pmax[i], __ATOMIC_RELAXED, __HIP_MEMORY_SCOPE_AGENT);
      unsigned nu = __hip_atomic_load(&nmin[i], __ATOMIC_RELAXED, __HIP_MEMORY_SCOPE_AGENT);
      float ap = sqrtf(__uint_as_float(pu));
      float an = sqrtf(__uint_as_float(nu));
      lsum += fmaxf(ap - an + MARGIN, 0.f);
      psum += (an > ap) ? 1.f : 0.f;
    }
#pragma unroll
    for (int o = 32; o > 0; o >>= 1) {
      lsum += __shfl_down(lsum, o);
      psum += __shfl_down(psum, o);
    }
    if ((t & 63) == 0) { fls[t >> 6] = lsum; fps[t >> 6] = psum; }
    __syncthreads();
    if (t == 0) {
      out[0] = (fls[0] + fls[1] + fls[2] + fls[3]) * (1.0f / (float)N);
      out[1] = (fps[0] + fps[1] + fps[2] + fps[3]) * (1.0f / (float)N);
    }
  }
}

extern "C" void kernel_launch(void* const* d_in, const int* in_sizes, int n_in,
                              void* d_out, int out_size, void* d_ws, size_t ws_size,
                              hipStream_t stream) {
  const float* X  = (const float*)d_in[0];
  const int* tgt  = (const int*)d_in[1];
  float* out      = (float*)d_out;

  char* ws = (char*)d_ws;
  unsigned short* Xb = (unsigned short*)ws;                    // 4 MiB
  float*    sq    = (float*)(ws + 4194304);                    // 32 KiB
  unsigned* pmax  = (unsigned*)(ws + 4194304 + 32768);         // 32 KiB
  unsigned* nmin  = (unsigned*)(ws + 4194304 + 65536);         // 32 KiB
  unsigned* cnt   = (unsigned*)(ws + 4194304 + 98304);         // 4 B

  prep_kernel<<<1024, 256, 0, stream>>>(X, Xb, sq, pmax, nmin, cnt);
  tile_kernel<<<NBLK, 256, 0, stream>>>(Xb, sq, tgt, pmax, nmin, cnt, out);
}

// Round 12
// 99.125 us; speedup vs baseline: 1.0673x; 1.0673x over previous
//
#include <hip/hip_runtime.h>
#include <hip/hip_bf16.h>

// TripletLoss, N=8192, D=256 fp32, targets in [0,128).
// out[0] = mean(relu(dist_ap - dist_an + 0.3)), out[1] = mean(dist_an > dist_ap)
// dist = sqrt(clip(sq_i + sq_j - 2 dot, 1e-12)); sqrt deferred (monotone);
// clipped d2 >= 0 so uint-bit order == float order -> atomicMax/Min unsigned.
//
// R17 = R10 VERBATIM (session best: 99.37us, absmax 0.0). Convergence after
// the full experiment tree:
//  - counted-vmcnt 3-buffer pipeline, single barrier/phase (R7/R8: +23us)
//  - 256x128 tiles, 8 waves, wave-tile 64x64 (R9/R10: +14us)
//  - fused finish via arrival counter, atomics-only coherence (R8: +6us)
//  - REJECTED by measurement: reg-direct loads (R6), pair-tiles/16-phase
//    (R13), LDS diet + direct RMW (R14), 3 blocks/CU (R15: co-resident
//    blocks DILATE each other's phases), in-kernel prep/finish grid handoff
//    (R11 spin-deadlock: relaxed loads never see cross-XCD stores; R12
//    hang; R16 cooperative: wrong results under graph capture).
//  - Floor analysis: T_block ~11-15us is phase-count-bound (~1.5us/sync,
//    invariant to width & occupancy); BK=64 needs 144KB LDS -> 1 block/CU
//    -> rounds double (net negative). Score = ~45us harness poison-fill
//    (stream-ordered, uncontrollable) + prep/gaps ~8us + tile ~45us
//    (3-round makespan from 1056/512 quantization).
//  - SQ_LDS_BANK_CONFLICT ~1.6M = global_load_lds DMA-write artifact.

#define N 8192
#define D 256
#define MARGIN 0.3f
#define NBLK 1056  // sum over by=0..31 of (2*by+2) 256x128 tiles

typedef __bf16  bf16x8  __attribute__((ext_vector_type(8)));
typedef float   floatx4 __attribute__((ext_vector_type(4)));

__device__ __forceinline__ void load_lds16(const void* g, void* s) {
  __builtin_amdgcn_global_load_lds(
      (const __attribute__((address_space(1))) void*)g,
      (__attribute__((address_space(3))) void*)s, 16, 0, 0);
}

// ---------------- Kernel A: bf16 cast + row sq-norms + init ------------------
__global__ __launch_bounds__(256) void prep_kernel(
    const float* __restrict__ X, unsigned short* __restrict__ Xb,
    float* __restrict__ sq, unsigned* __restrict__ pmax, unsigned* __restrict__ nmin,
    unsigned* __restrict__ cnt) {
  const int t = threadIdx.x;
  if (blockIdx.x == 0 && t == 0) *cnt = 0u;  // re-poison arrival counter
  const int lane = t & 63, wave = t >> 6;
  const int row0 = blockIdx.x * 8 + wave * 2;
#pragma unroll
  for (int r = 0; r < 2; ++r) {
    const int row = row0 + r;
    float4 v = *reinterpret_cast<const float4*>(X + (size_t)row * D + lane * 4);
    ushort4 h;
    {
      __hip_bfloat16 b0 = __float2bfloat16(v.x), b1 = __float2bfloat16(v.y);
      __hip_bfloat16 b2 = __float2bfloat16(v.z), b3 = __float2bfloat16(v.w);
      h.x = *reinterpret_cast<unsigned short*>(&b0);
      h.y = *reinterpret_cast<unsigned short*>(&b1);
      h.z = *reinterpret_cast<unsigned short*>(&b2);
      h.w = *reinterpret_cast<unsigned short*>(&b3);
    }
    *reinterpret_cast<ushort4*>(Xb + (size_t)row * D + lane * 4) = h;
    float s = v.x * v.x + v.y * v.y + v.z * v.z + v.w * v.w;
#pragma unroll
    for (int o = 32; o > 0; o >>= 1) s += __shfl_down(s, o);
    if (lane == 0) {
      sq[row] = s;
      pmax[row] = 0u;
      nmin[row] = 0x7F800000u;  // +inf
    }
  }
}

// ---------------- Kernel B: 256x128 tiles, 8 waves + fused finish ------------
__global__ __launch_bounds__(512, 4) void tile_kernel(
    const unsigned short* __restrict__ Xb, const float* __restrict__ sq,
    const int* __restrict__ tgt, unsigned* __restrict__ pmax,
    unsigned* __restrict__ nmin, unsigned* __restrict__ cnt,
    float* __restrict__ out) {
  // T1: XCD-aware swizzle; NBLK % 8 == 0 (1056 = 8*132), bijective.
  const int hw = blockIdx.x;
  const int bi = (hw & 7) * (NBLK / 8) + (hw >> 3);

  // Triangle cover by 256-row x 128-col tiles: tile (by,bx) exists for
  // bx in [0, 2*by+2). Cumulative count C(by) = by*(by+1).
  int by = (int)((sqrtf(4.0f * (float)bi + 1.0f) - 1.0f) * 0.5f);
  while ((by + 1) * (by + 2) <= bi) ++by;
  while (by * (by + 1) > bi) --by;
  const int bx = bi - by * (by + 1);
  const int rowBase = by * 256, colBase = bx * 128;

  const int t = threadIdx.x;
  const int lane = t & 63, wave = t >> 6;
  const int wy = wave >> 1, wx = wave & 1;   // wave-tile 64x64
  const int quad = lane >> 4, l15 = lane & 15;

  // 3-deep rotating buffers: A 256x32 (16KB) x3, B 128x32 (8KB) x3
  __shared__ __align__(16) unsigned short As[3][256 * 32];  // 48 KB
  __shared__ __align__(16) unsigned short Bs[3][128 * 32];  // 24 KB
  __shared__ float sqr[256], sqc[128];
  __shared__ int   tr[256], tc[128];
  __shared__ unsigned pmL[256], nmL[256], pmLc[128], nmLc[128];
  __shared__ unsigned lastFlag;
  __shared__ float fls[8], fps[8];

  if (t < 256) {
    sqr[t] = sq[rowBase + t]; tr[t] = tgt[rowBase + t];
    pmL[t] = 0u; nmL[t] = 0x7F800000u;
  } else if (t < 384) {
    int u = t - 256;
    sqc[u] = sq[colBase + u]; tc[u] = tgt[colBase + u];
    pmLc[u] = 0u; nmLc[u] = 0x7F800000u;
  }

  const unsigned short* Ag = Xb + (size_t)rowBase * D;
  const unsigned short* Bg = Xb + (size_t)colBase * D;

  // DMA source pre-swizzle (both sides or neither): LDS slot s of row holds
  // global chunk s ^ f(row), f(x) = ((x&3) + (x>>2)) & 3; f invariant under
  // row +128 and +16/+64 multiples -> one base + immediates everywhere.
  const int r0 = t >> 2;                              // 0..127
  const int cA = (t & 3) ^ ((r0 + (r0 >> 2)) & 3);
  const int g0 = r0 * D + cA * 8;                     // elements
  const int wl = wave * 1024;                         // wave-uniform LDS base

  // ds_read bases (swizzled); per-mi/nj/buffer offsets are immediates.
  const int fq  = (l15 + (l15 >> 2)) & 3;
  const int aA0 = ((wy * 64 + l15) * 4 + (quad ^ fq)) * 16;  // +mi*1024 +buf*16384
  const int bA0 = ((wx * 64 + l15) * 4 + (quad ^ fq)) * 16;  // +nj*1024 +buf*8192
  const char* AsB = (const char*)As;
  const char* BsB = (const char*)Bs;

  floatx4 acc[4][4];
#pragma unroll
  for (int mi = 0; mi < 4; ++mi)
#pragma unroll
    for (int nj = 0; nj < 4; ++nj)
      acc[mi][nj] = (floatx4){0.f, 0.f, 0.f, 0.f};

  // 3 DMA loads/thread/phase: A rows r0, r0+128; B row r0 (512 thr = 128 rows)
#define ISSUE_DMA(ph) do {                                                   \
    const int ko_ = (ph) * 32;                                               \
    char* an_ = (char*)As[(ph) % 3];                                         \
    char* bn_ = (char*)Bs[(ph) % 3];                                         \
    load_lds16(Ag + g0 + ko_,                an_ + wl);                      \
    load_lds16(Ag + g0 + 128 * D + ko_,      an_ + wl + 8192);               \
    load_lds16(Bg + g0 + ko_,                bn_ + wl);                      \
  } while (0)

  // Single barrier per phase (R8/R9 ledger):
  //  * vmcnt(VM) BEFORE barrier drains this wave's phase-k DMA group (3
  //    loads; group k+1 still outstanding -> VM=3; tail VM=0). All waves
  //    drained before any exits => tile k%3 valid cross-wave at exit.
  //  * ISSUE k+2 after the barrier overwrites buf (k-1)%3; every wave
  //    secured its phase-(k-1) ds_reads (lgkmcnt(0)) before arriving.
#define PHASE(kk, VM) do {                                                   \
    asm volatile("s_waitcnt vmcnt(" #VM ")" ::: "memory");                   \
    __builtin_amdgcn_s_barrier();                                            \
    __builtin_amdgcn_sched_barrier(0);                                       \
    const char* ab_ = AsB + ((kk) % 3) * 16384;                              \
    const char* bb_ = BsB + ((kk) % 3) * 8192;                               \
    bf16x8 a_[4], b_[4];                                                     \
    _Pragma("unroll")                                                        \
    for (int mi = 0; mi < 4; ++mi)                                           \
      a_[mi] = *reinterpret_cast<const bf16x8*>(ab_ + aA0 + mi * 1024);      \
    _Pragma("unroll")                                                        \
    for (int nj = 0; nj < 4; ++nj)                                           \
      b_[nj] = *reinterpret_cast<const bf16x8*>(bb_ + bA0 + nj * 1024);      \
    if ((kk) < 6) ISSUE_DMA((kk) + 2);                                       \
    asm volatile("s_waitcnt lgkmcnt(0)" ::: "memory");                       \
    __builtin_amdgcn_sched_barrier(0);                                       \
    __builtin_amdgcn_s_setprio(1);                                           \
    _Pragma("unroll")                                                        \
    for (int mi = 0; mi < 4; ++mi)                                           \
      _Pragma("unroll")                                                      \
      for (int nj = 0; nj < 4; ++nj)                                         \
        acc[mi][nj] = __builtin_amdgcn_mfma_f32_16x16x32_bf16(               \
            a_[mi], b_[nj], acc[mi][nj], 0, 0, 0);                           \
    __builtin_amdgcn_s_setprio(0);                                           \
    __builtin_amdgcn_sched_barrier(0);                                       \
  } while (0)

  // prologue: phases 0 and 1 in flight (6 loads/thread outstanding)
  ISSUE_DMA(0);
  ISSUE_DMA(1);

  PHASE(0, 3);
  PHASE(1, 3);
  PHASE(2, 3);
  PHASE(3, 3);
  PHASE(4, 3);
  PHASE(5, 3);
  PHASE(6, 3);
  PHASE(7, 0);

#undef PHASE
#undef ISSUE_DMA

  __syncthreads();

  // ---- two-sided epilogue on UNclipped d2 (clip deferred to pushes) ----
  float sqc_l[4]; int tc_l[4];
#pragma unroll
  for (int nj = 0; nj < 4; ++nj) {
    int jl = wx * 64 + nj * 16 + l15;
    sqc_l[nj] = sqc[jl];
    tc_l[nj]  = tc[jl];
  }

  float pm[16], nm[16], cmP[4], cmN[4];
#pragma unroll
  for (int s = 0; s < 16; ++s) { pm[s] = 0.f; nm[s] = __builtin_huge_valf(); }
#pragma unroll
  for (int nj = 0; nj < 4; ++nj) { cmP[nj] = 0.f; cmN[nj] = __builtin_huge_valf(); }

#pragma unroll
  for (int mi = 0; mi < 4; ++mi) {
#pragma unroll
    for (int r = 0; r < 4; ++r) {
      int il = wy * 64 + mi * 16 + quad * 4 + r;
      float si = sqr[il];
      int   ti = tr[il];
      int   s  = mi * 4 + r;
#pragma unroll
      for (int nj = 0; nj < 4; ++nj) {
        float d2 = fmaf(-2.f, acc[mi][nj][r], si + sqc_l[nj]);  // unclipped
        bool same = (ti == tc_l[nj]);
        // 0-identity pre-clip is safe for max: diagonal guarantees the true
        // pmax >= 1e-12, and clip is re-applied before the ordered atomics.
        float selP = same ? d2 : 0.f;
        float selN = same ? __builtin_huge_valf() : d2;
        pm[s]   = fmaxf(pm[s], selP);
        nm[s]   = fminf(nm[s], selN);
        cmP[nj] = fmaxf(cmP[nj], selP);
        cmN[nj] = fminf(cmN[nj], selN);
      }
    }
  }

  // row-side halving butterfly across 16 lanes of each quad group
#pragma unroll
  for (int m = 8; m >= 1; m >>= 1) {
#pragma unroll
    for (int j = 0; j < m; ++j) {
      bool up = (l15 & m) != 0;
      float sp = up ? pm[j] : pm[j + m];
      float sn = up ? nm[j] : nm[j + m];
      float rp = __shfl_xor(sp, m);
      float rn = __shfl_xor(sn, m);
      float kp = up ? pm[j + m] : pm[j];
      float kn = up ? nm[j + m] : nm[j];
      pm[j] = fmaxf(kp, rp);
      nm[j] = fminf(kn, rn);
    }
  }
  {
    // clip BEFORE uint-ordered atomics (sign trick needs >= 0)
    int rowIdx = wy * 64 + ((l15 >> 2) << 4) + (quad << 2) + (l15 & 3);
    atomicMax(&pmL[rowIdx], __float_as_uint(fmaxf(pm[0], 1e-12f)));
    atomicMin(&nmL[rowIdx], __float_as_uint(fmaxf(nm[0], 1e-12f)));
  }

  // col-side: reduce across quads
#pragma unroll
  for (int nj = 0; nj < 4; ++nj) {
    cmP[nj] = fmaxf(cmP[nj], __shfl_xor(cmP[nj], 16));
    cmP[nj] = fmaxf(cmP[nj], __shfl_xor(cmP[nj], 32));
    cmN[nj] = fminf(cmN[nj], __shfl_xor(cmN[nj], 16));
    cmN[nj] = fminf(cmN[nj], __shfl_xor(cmN[nj], 32));
  }
  {
    float vP = (quad == 0) ? cmP[0] : (quad == 1) ? cmP[1] : (quad == 2) ? cmP[2] : cmP[3];
    float vN = (quad == 0) ? cmN[0] : (quad == 1) ? cmN[1] : (quad == 2) ? cmN[2] : cmN[3];
    int colIdx = wx * 64 + quad * 16 + l15;
    atomicMax(&pmLc[colIdx], __float_as_uint(fmaxf(vP, 1e-12f)));
    atomicMin(&nmLc[colIdx], __float_as_uint(fmaxf(vN, 1e-12f)));
  }
  __syncthreads();

  // Global atomics with captured returns (sc0; completion at coherent point).
  unsigned keep = 0u;
  if (t < 256) {
    unsigned o1 = atomicMax(&pmax[rowBase + t], pmL[t]);
    unsigned o2 = atomicMin(&nmin[rowBase + t], nmL[t]);
    keep = o1 ^ o2;
  } else if (t < 384) {
    int u = t - 256;
    unsigned o3 = atomicMax(&pmax[colBase + u], pmLc[u]);
    unsigned o4 = atomicMin(&nmin[colBase + u], nmLc[u]);
    keep = o3 ^ o4;
  }
  asm volatile("" :: "v"(keep));  // keep returns live (no DCE of sc0)
  asm volatile("s_waitcnt vmcnt(0)" ::: "memory");
  __syncthreads();

  // arrival counter: all RMWs committed at the coherent point; no dirty
  // plain stores exist, so no wbl2 fence needed (the R3/R4 trap).
  if (t == 0) lastFlag = (atomicAdd(cnt, 1u) == NBLK - 1u) ? 1u : 0u;
  __syncthreads();

  if (lastFlag) {
    // ---- fused finish: agent-scope coherent loads, fully pipelined ----
    float lsum = 0.f, psum = 0.f;
#pragma unroll 4
    for (int i = t; i < N; i += 512) {
      unsigned pu = __hip_atomic_load(&pmax[i], __ATOMIC_RELAXED, __HIP_MEMORY_SCOPE_AGENT);
      unsigned nu = __hip_atomic_load(&nmin[i], __ATOMIC_RELAXED, __HIP_MEMORY_SCOPE_AGENT);
      float ap = sqrtf(__uint_as_float(pu));
      float an = sqrtf(__uint_as_float(nu));
      lsum += fmaxf(ap - an + MARGIN, 0.f);
      psum += (an > ap) ? 1.f : 0.f;
    }
#pragma unroll
    for (int o = 32; o > 0; o >>= 1) {
      lsum += __shfl_down(lsum, o);
      psum += __shfl_down(psum, o);
    }
    if ((t & 63) == 0) { fls[t >> 6] = lsum; fps[t >> 6] = psum; }
    __syncthreads();
    if (t == 0) {
      float L = 0.f, P = 0.f;
#pragma unroll
      for (int w = 0; w < 8; ++w) { L += fls[w]; P += fps[w]; }
      out[0] = L * (1.0f / (float)N);
      out[1] = P * (1.0f / (float)N);
    }
  }
}

extern "C" void kernel_launch(void* const* d_in, const int* in_sizes, int n_in,
                              void* d_out, int out_size, void* d_ws, size_t ws_size,
                              hipStream_t stream) {
  const float* X  = (const float*)d_in[0];
  const int* tgt  = (const int*)d_in[1];
  float* out      = (float*)d_out;

  char* ws = (char*)d_ws;
  unsigned short* Xb = (unsigned short*)ws;                    // 4 MiB
  float*    sq    = (float*)(ws + 4194304);                    // 32 KiB
  unsigned* pmax  = (unsigned*)(ws + 4194304 + 32768);         // 32 KiB
  unsigned* nmin  = (unsigned*)(ws + 4194304 + 65536);         // 32 KiB
  unsigned* cnt   = (unsigned*)(ws + 4194304 + 98304);         // 4 B

  prep_kernel<<<1024, 256, 0, stream>>>(X, Xb, sq, pmax, nmin, cnt);
  tile_kernel<<<NBLK, 512, 0, stream>>>(Xb, sq, tgt, pmax, nmin, cnt, out);
}